// Round 1
// baseline (9968.845 us; speedup 1.0000x reference)
//
#include <hip/hip_runtime.h>

#define SEQ   512
#define BATCH 64
#define D_IN  1024
#define D_LAT 1024
#define D_CAT 2048
#define NBLK  128      // j-blocks; each owns 8 output columns (j) x 4 gates = 32 W rows
#define JPB   8
#define ROWS  32
#define THREADS 512    // 8 waves: waves 0-3 = h-half (k<1024), waves 4-7 = x-half

typedef unsigned short u16;
typedef __attribute__((ext_vector_type(8))) short short8;   // bf16x8 MFMA frag (4 VGPRs)
typedef __attribute__((ext_vector_type(4))) float floatx4;  // fp32x4 accumulator

__device__ __forceinline__ u16 f2bf(float f) {
    union { float f; unsigned u; } a; a.f = f;
    unsigned u = a.u;
    return (u16)((u + 0x7FFFu + ((u >> 16) & 1u)) >> 16);   // RNE
}

__device__ __forceinline__ float sigm(float x)  { return 1.0f / (1.0f + __expf(-x)); }
__device__ __forceinline__ float tanhf_(float x){ return 2.0f / (1.0f + __expf(-2.0f * x)) - 1.0f; }

// Device-scope grid barrier. counter=bar[0], gen=bar[1]; both zeroed pre-launch.
__device__ __forceinline__ void gridbar(unsigned* bar, int step) {
    __syncthreads();                       // all waves' stores drained (vmcnt0 at s_barrier)
    if (threadIdx.x == 0) {
        __builtin_amdgcn_fence(__ATOMIC_RELEASE, "agent");   // waitcnt + L2 writeback
        unsigned prev = __hip_atomic_fetch_add(&bar[0], 1u, __ATOMIC_RELAXED,
                                               __HIP_MEMORY_SCOPE_AGENT);
        unsigned target = (unsigned)(step + 1) * NBLK;
        if (prev == target - 1u) {
            __hip_atomic_store(&bar[1], (unsigned)(step + 1), __ATOMIC_RELAXED,
                               __HIP_MEMORY_SCOPE_AGENT);
        } else {
            while (__hip_atomic_load(&bar[1], __ATOMIC_RELAXED,
                                     __HIP_MEMORY_SCOPE_AGENT) < (unsigned)(step + 1)) {
                __builtin_amdgcn_s_sleep(1);
            }
        }
        __builtin_amdgcn_fence(__ATOMIC_ACQUIRE, "agent");   // invalidate stale lines
    }
    __syncthreads();
}

__global__ void cvt_bf16(const float* __restrict__ x, u16* __restrict__ xb, int n8) {
    int i = blockIdx.x * blockDim.x + threadIdx.x;
    int stride = gridDim.x * blockDim.x;
    for (; i < n8; i += stride) {
        float4 v0 = ((const float4*)x)[2 * i];
        float4 v1 = ((const float4*)x)[2 * i + 1];
        short8 o;
        o[0] = (short)f2bf(v0.x); o[1] = (short)f2bf(v0.y);
        o[2] = (short)f2bf(v0.z); o[3] = (short)f2bf(v0.w);
        o[4] = (short)f2bf(v1.x); o[5] = (short)f2bf(v1.y);
        o[6] = (short)f2bf(v1.z); o[7] = (short)f2bf(v1.w);
        *(short8*)(xb + 8 * (size_t)i) = o;
    }
}

__launch_bounds__(THREADS, 1)
__global__ void lstm_persist(const float* __restrict__ Wf, const float* __restrict__ bfp,
                             const float* __restrict__ Wi, const float* __restrict__ bip,
                             const float* __restrict__ Wo, const float* __restrict__ bop,
                             const float* __restrict__ Wc, const float* __restrict__ bcp,
                             const u16* __restrict__ xb,     // [SEQ*BATCH*D_IN] bf16
                             u16* __restrict__ hhist,        // [(SEQ+1)*BATCH*D_LAT] bf16
                             float* __restrict__ out,        // [SEQ*BATCH*D_LAT]
                             unsigned* __restrict__ bar) {
    // LDS: weights (rows padded +8 bf16 -> stride 4112B: conflict-free b128 reads)
    __shared__ __align__(16) u16 Wlds[ROWS][D_CAT + 8];      // 131584 B
    __shared__ float gatesA[ROWS * 65];                      // 8320 B (h-half partials)
    __shared__ float gatesB[ROWS * 65];                      // 8320 B (x-half partials)
    __shared__ float biasL[ROWS];

    const int tid  = threadIdx.x;
    const int jblk = blockIdx.x;
    const int wave = tid >> 6;
    const int lane = tid & 63;

    // ---- one-time: stage this block's 32 weight rows into LDS as bf16 ----
    for (int g = 0; g < 4; ++g) {
        const float* W = (g == 0) ? Wf : (g == 1) ? Wi : (g == 2) ? Wo : Wc;
        for (int jj2 = 0; jj2 < JPB; ++jj2) {
            const float* src = W + (size_t)(jblk * JPB + jj2) * D_CAT;
            float4 v = ((const float4*)src)[tid];            // tid in [0,512) == D_CAT/4
            int r = g * JPB + jj2;
            Wlds[r][tid * 4 + 0] = f2bf(v.x);
            Wlds[r][tid * 4 + 1] = f2bf(v.y);
            Wlds[r][tid * 4 + 2] = f2bf(v.z);
            Wlds[r][tid * 4 + 3] = f2bf(v.w);
        }
    }
    if (tid < ROWS) {
        const float* bsrc = (tid < 8) ? bfp : (tid < 16) ? bip : (tid < 24) ? bop : bcp;
        biasL[tid] = bsrc[jblk * JPB + (tid & 7)];
    }
    __syncthreads();

    const int half  = wave >> 2;        // 0: h-part (k<1024), 1: x-part
    const int bt    = wave & 3;         // batch tile (16 each)
    const int m     = lane & 15;        // A row (batch in tile) == B col (W row in tile)
    const int q     = lane >> 4;        // k-quad
    const int koff  = q * 8;
    const int bglob = bt * 16 + m;
    const int wcol  = half * 1024;      // W column offset for this half
    float* gd = half ? gatesB : gatesA;

    float creg = 0.0f;                  // c state for (b=lane, jj=wave), lives all 512 steps

    #pragma unroll 1
    for (int t = 0; t < SEQ; ++t) {
        const u16* zsrc = half ? (xb + (size_t)t * (BATCH * D_IN))
                               : (hhist + (size_t)t * (BATCH * D_LAT));
        const u16* aptr = zsrc + (size_t)bglob * 1024 + koff;

        floatx4 acc0 = {0.f, 0.f, 0.f, 0.f};
        floatx4 acc1 = {0.f, 0.f, 0.f, 0.f};
        #pragma unroll 8
        for (int kk = 0; kk < 32; ++kk) {
            short8 a  = *(const short8*)(aptr + kk * 32);
            short8 b0 = *(const short8*)&Wlds[m][wcol + koff + kk * 32];
            short8 b1 = *(const short8*)&Wlds[16 + m][wcol + koff + kk * 32];
            acc0 = __builtin_amdgcn_mfma_f32_16x16x32_bf16(a, b0, acc0, 0, 0, 0);
            acc1 = __builtin_amdgcn_mfma_f32_16x16x32_bf16(a, b1, acc1, 0, 0, 0);
        }

        // C-layout: n(row-in-tile)=lane&15, m(batch-in-tile)=q*4+reg
        #pragma unroll
        for (int r = 0; r < 4; ++r) {
            int bb = bt * 16 + q * 4 + r;
            gd[m * 65 + bb]        = acc0[r];
            gd[(16 + m) * 65 + bb] = acc1[r];
        }
        __syncthreads();

        // elementwise: thread -> (b=lane, jj=wave); rows: f=jj, i=8+jj, o=16+jj, g=24+jj
        {
            const int jj = wave;
            const int b  = lane;
            float pf = gatesA[jj * 65 + b]        + gatesB[jj * 65 + b]        + biasL[jj];
            float pi = gatesA[(8 + jj) * 65 + b]  + gatesB[(8 + jj) * 65 + b]  + biasL[8 + jj];
            float po = gatesA[(16 + jj) * 65 + b] + gatesB[(16 + jj) * 65 + b] + biasL[16 + jj];
            float pg = gatesA[(24 + jj) * 65 + b] + gatesB[(24 + jj) * 65 + b] + biasL[24 + jj];
            float ft = sigm(pf), it = sigm(pi), ot = sigm(po), gt = tanhf_(pg);
            creg = ft * creg + it * gt;
            float h = ot * tanhf_(creg);
            int jglob = jblk * JPB + jj;
            hhist[(size_t)(t + 1) * (BATCH * D_LAT) + (size_t)b * D_LAT + jglob] = f2bf(h);
            out[(size_t)t * (BATCH * D_LAT) + (size_t)b * D_LAT + jglob] = h;
        }

        gridbar(bar, t);
    }
}

extern "C" void kernel_launch(void* const* d_in, const int* in_sizes, int n_in,
                              void* d_out, int out_size, void* d_ws, size_t ws_size,
                              hipStream_t stream) {
    const float* x  = (const float*)d_in[0];
    const float* Wf = (const float*)d_in[1];
    const float* bf = (const float*)d_in[2];
    const float* Wi = (const float*)d_in[3];
    const float* bi = (const float*)d_in[4];
    const float* Wo = (const float*)d_in[5];
    const float* bo = (const float*)d_in[6];
    const float* Wc = (const float*)d_in[7];
    const float* bc = (const float*)d_in[8];
    float* out = (float*)d_out;

    char* ws = (char*)d_ws;
    unsigned* bar = (unsigned*)ws;
    u16* hhist = (u16*)(ws + 1024);                                      // 513*64*1024*2 B
    u16* xb    = (u16*)(ws + 1024 + (size_t)(SEQ + 1) * BATCH * D_LAT * 2);

    // zero barrier vars + h_hist[0] (contiguous region)
    hipMemsetAsync(ws, 0, 1024 + (size_t)BATCH * D_LAT * 2, stream);
    cvt_bf16<<<2048, 256, 0, stream>>>(x, xb, SEQ * BATCH * D_IN / 8);
    lstm_persist<<<NBLK, THREADS, 0, stream>>>(Wf, bf, Wi, bi, Wo, bo, Wc, bc,
                                               xb, hhist, out, bar);
}

// Round 2
// 5713.536 us; speedup vs baseline: 1.7448x; 1.7448x over previous
//
#include <hip/hip_runtime.h>

#define SEQ   512
#define BATCH 64
#define D_IN  1024
#define D_LAT 1024
#define D_CAT 2048
#define NBLK  128      // j-blocks; each owns 8 output columns (j) x 4 gates = 32 W rows
#define JPB   8
#define ROWS  32
#define THREADS 512    // 8 waves: waves 0-3 = h-half (k<1024), waves 4-7 = x-half

typedef unsigned short u16;
typedef __attribute__((ext_vector_type(8))) short short8;   // bf16x8 MFMA frag (4 VGPRs)
typedef __attribute__((ext_vector_type(4))) float floatx4;  // fp32x4 accumulator

__device__ __forceinline__ u16 f2bf(float f) {
    union { float f; unsigned u; } a; a.f = f;
    unsigned u = a.u;
    return (u16)((u + 0x7FFFu + ((u >> 16) & 1u)) >> 16);   // RNE
}

__device__ __forceinline__ float sigm(float x)  { return 1.0f / (1.0f + __expf(-x)); }
__device__ __forceinline__ float tanhf_(float x){ return 2.0f / (1.0f + __expf(-2.0f * x)) - 1.0f; }

// Device-scope grid barrier, NO cache-maintenance fences.
// Safety argument: (1) h-stores are sc1 write-through (agent-scope relaxed
// atomics) and are vmcnt-drained by the __syncthreads before arrival, so they
// are at the coherence point before bar[0] is bumped. (2) h-loads use fresh
// addresses (hhist[t] written exactly once, read only after the barrier), so
// no cache can hold a stale copy. (3) bar[] accesses are agent-scope atomics
// (proven to observe remote-XCD stores in round 1's spin loop).
__device__ __forceinline__ void gridbar(unsigned* bar, int step) {
    __syncthreads();   // emits s_waitcnt vmcnt(0) lgkmcnt(0) + s_barrier
    if (threadIdx.x == 0) {
        unsigned prev = __hip_atomic_fetch_add(&bar[0], 1u, __ATOMIC_RELAXED,
                                               __HIP_MEMORY_SCOPE_AGENT);
        unsigned target = (unsigned)(step + 1) * NBLK;
        if (prev == target - 1u) {
            __hip_atomic_store(&bar[1], (unsigned)(step + 1), __ATOMIC_RELAXED,
                               __HIP_MEMORY_SCOPE_AGENT);
        } else {
            while (__hip_atomic_load(&bar[1], __ATOMIC_RELAXED,
                                     __HIP_MEMORY_SCOPE_AGENT) < (unsigned)(step + 1)) {
                __builtin_amdgcn_s_sleep(1);
            }
        }
    }
    __syncthreads();
    asm volatile("" ::: "memory");   // keep next step's loads below the barrier
}

__global__ void cvt_bf16(const float* __restrict__ x, u16* __restrict__ xb, int n8) {
    int i = blockIdx.x * blockDim.x + threadIdx.x;
    int stride = gridDim.x * blockDim.x;
    for (; i < n8; i += stride) {
        float4 v0 = ((const float4*)x)[2 * i];
        float4 v1 = ((const float4*)x)[2 * i + 1];
        short8 o;
        o[0] = (short)f2bf(v0.x); o[1] = (short)f2bf(v0.y);
        o[2] = (short)f2bf(v0.z); o[3] = (short)f2bf(v0.w);
        o[4] = (short)f2bf(v1.x); o[5] = (short)f2bf(v1.y);
        o[6] = (short)f2bf(v1.z); o[7] = (short)f2bf(v1.w);
        *(short8*)(xb + 8 * (size_t)i) = o;
    }
}

__launch_bounds__(THREADS, 1)
__global__ void lstm_persist(const float* __restrict__ Wf, const float* __restrict__ bfp,
                             const float* __restrict__ Wi, const float* __restrict__ bip,
                             const float* __restrict__ Wo, const float* __restrict__ bop,
                             const float* __restrict__ Wc, const float* __restrict__ bcp,
                             const u16* __restrict__ xb,     // [SEQ*BATCH*D_IN] bf16
                             u16* __restrict__ hhist,        // [(SEQ+1)*BATCH*D_LAT] bf16
                             float* __restrict__ out,        // [SEQ*BATCH*D_LAT]
                             unsigned* __restrict__ bar) {
    // LDS: weights (rows padded +8 bf16 -> stride 4112B)
    __shared__ __align__(16) u16 Wlds[ROWS][D_CAT + 8];      // 131584 B
    __shared__ float gatesA[ROWS * 65];                      // 8320 B (h-half partials)
    __shared__ float gatesB[ROWS * 65];                      // 8320 B (x-half partials)
    __shared__ float biasL[ROWS];

    const int tid  = threadIdx.x;
    const int jblk = blockIdx.x;
    const int wave = tid >> 6;
    const int lane = tid & 63;

    // ---- one-time: stage this block's 32 weight rows into LDS as bf16 ----
    for (int g = 0; g < 4; ++g) {
        const float* W = (g == 0) ? Wf : (g == 1) ? Wi : (g == 2) ? Wo : Wc;
        for (int jj2 = 0; jj2 < JPB; ++jj2) {
            const float* src = W + (size_t)(jblk * JPB + jj2) * D_CAT;
            float4 v = ((const float4*)src)[tid];            // tid in [0,512) == D_CAT/4
            int r = g * JPB + jj2;
            Wlds[r][tid * 4 + 0] = f2bf(v.x);
            Wlds[r][tid * 4 + 1] = f2bf(v.y);
            Wlds[r][tid * 4 + 2] = f2bf(v.z);
            Wlds[r][tid * 4 + 3] = f2bf(v.w);
        }
    }
    if (tid < ROWS) {
        const float* bsrc = (tid < 8) ? bfp : (tid < 16) ? bip : (tid < 24) ? bop : bcp;
        biasL[tid] = bsrc[jblk * JPB + (tid & 7)];
    }
    __syncthreads();

    const int half  = wave >> 2;        // 0: h-part (k<1024), 1: x-part
    const int bt    = wave & 3;         // batch tile (16 each)
    const int m     = lane & 15;        // A row (batch in tile) == B col (W row in tile)
    const int q     = lane >> 4;        // k-quad
    const int koff  = q * 8;
    const int bglob = bt * 16 + m;
    const int wcol  = half * 1024;      // W column offset for this half
    float* gd = half ? gatesB : gatesA;

    // combine mapping: threads 0..255 -> (b = tid>>2, jpair a = tid&3)
    const int cb = tid >> 2;            // batch (valid for tid<256)
    const int ca = tid & 3;             // j pair -> jj = {2a, 2a+1}
    float creg0 = 0.0f, creg1 = 0.0f;   // c state, lives all 512 steps

    #pragma unroll 1
    for (int t = 0; t < SEQ; ++t) {
        const u16* zsrc = half ? (xb + (size_t)t * (BATCH * D_IN))
                               : (hhist + (size_t)t * (BATCH * D_LAT));
        const u16* aptr = zsrc + (size_t)bglob * 1024 + koff;

        floatx4 acc0 = {0.f, 0.f, 0.f, 0.f};
        floatx4 acc1 = {0.f, 0.f, 0.f, 0.f};
        #pragma unroll 8
        for (int kk = 0; kk < 32; ++kk) {
            short8 a  = *(const short8*)(aptr + kk * 32);
            short8 b0 = *(const short8*)&Wlds[m][wcol + koff + kk * 32];
            short8 b1 = *(const short8*)&Wlds[16 + m][wcol + koff + kk * 32];
            acc0 = __builtin_amdgcn_mfma_f32_16x16x32_bf16(a, b0, acc0, 0, 0, 0);
            acc1 = __builtin_amdgcn_mfma_f32_16x16x32_bf16(a, b1, acc1, 0, 0, 0);
        }

        // C-layout: n(row-in-tile)=lane&15, m(batch-in-tile)=q*4+reg
        #pragma unroll
        for (int r = 0; r < 4; ++r) {
            int bb = bt * 16 + q * 4 + r;
            gd[m * 65 + bb]        = acc0[r];
            gd[(16 + m) * 65 + bb] = acc1[r];
        }
        __syncthreads();

        // elementwise: threads 0..255, each does jj = 2a and 2a+1 for batch cb
        if (tid < 256) {
            float h0, h1;
            {
                const int jj = 2 * ca;
                float pf = gatesA[jj * 65 + cb]        + gatesB[jj * 65 + cb]        + biasL[jj];
                float pi = gatesA[(8 + jj) * 65 + cb]  + gatesB[(8 + jj) * 65 + cb]  + biasL[8 + jj];
                float po = gatesA[(16 + jj) * 65 + cb] + gatesB[(16 + jj) * 65 + cb] + biasL[16 + jj];
                float pg = gatesA[(24 + jj) * 65 + cb] + gatesB[(24 + jj) * 65 + cb] + biasL[24 + jj];
                float ft = sigm(pf), it = sigm(pi), ot = sigm(po), gt = tanhf_(pg);
                creg0 = ft * creg0 + it * gt;
                h0 = ot * tanhf_(creg0);
            }
            {
                const int jj = 2 * ca + 1;
                float pf = gatesA[jj * 65 + cb]        + gatesB[jj * 65 + cb]        + biasL[jj];
                float pi = gatesA[(8 + jj) * 65 + cb]  + gatesB[(8 + jj) * 65 + cb]  + biasL[8 + jj];
                float po = gatesA[(16 + jj) * 65 + cb] + gatesB[(16 + jj) * 65 + cb] + biasL[16 + jj];
                float pg = gatesA[(24 + jj) * 65 + cb] + gatesB[(24 + jj) * 65 + cb] + biasL[24 + jj];
                float ft = sigm(pf), it = sigm(pi), ot = sigm(po), gt = tanhf_(pg);
                creg1 = ft * creg1 + it * gt;
                h1 = ot * tanhf_(creg1);
            }
            const int jglob = jblk * JPB + 2 * ca;
            // packed sc1 write-through h store (2 x bf16 in one u32)
            unsigned hv = (unsigned)f2bf(h0) | ((unsigned)f2bf(h1) << 16);
            unsigned* hp = (unsigned*)(hhist + (size_t)(t + 1) * (BATCH * D_LAT)
                                             + (size_t)cb * D_LAT + jglob);
            __hip_atomic_store(hp, hv, __ATOMIC_RELAXED, __HIP_MEMORY_SCOPE_AGENT);
            // fp32 out store (8B)
            float2 ov = make_float2(h0, h1);
            *(float2*)(out + (size_t)t * (BATCH * D_LAT) + (size_t)cb * D_LAT + jglob) = ov;
        }

        gridbar(bar, t);
    }
}

extern "C" void kernel_launch(void* const* d_in, const int* in_sizes, int n_in,
                              void* d_out, int out_size, void* d_ws, size_t ws_size,
                              hipStream_t stream) {
    const float* x  = (const float*)d_in[0];
    const float* Wf = (const float*)d_in[1];
    const float* bf = (const float*)d_in[2];
    const float* Wi = (const float*)d_in[3];
    const float* bi = (const float*)d_in[4];
    const float* Wo = (const float*)d_in[5];
    const float* bo = (const float*)d_in[6];
    const float* Wc = (const float*)d_in[7];
    const float* bc = (const float*)d_in[8];
    float* out = (float*)d_out;

    char* ws = (char*)d_ws;
    unsigned* bar = (unsigned*)ws;
    u16* hhist = (u16*)(ws + 1024);                                      // 513*64*1024*2 B
    u16* xb    = (u16*)(ws + 1024 + (size_t)(SEQ + 1) * BATCH * D_LAT * 2);

    // zero barrier vars + h_hist[0] (contiguous region)
    hipMemsetAsync(ws, 0, 1024 + (size_t)BATCH * D_LAT * 2, stream);
    cvt_bf16<<<2048, 256, 0, stream>>>(x, xb, SEQ * BATCH * D_IN / 8);
    lstm_persist<<<NBLK, THREADS, 0, stream>>>(Wf, bf, Wi, bi, Wo, bo, Wc, bc,
                                               xb, hhist, out, bar);
}